// Round 1
// baseline (1105.996 us; speedup 1.0000x reference)
//
#include <hip/hip_runtime.h>
#include <hip/hip_bf16.h>
#include <math.h>

// Problem constants (fixed by setup_inputs)
#define BS 2
#define NW 5
#define NS 5
#define NQ 5
#define FDIM 64
#define FH 21
#define FW 21
#define NPOS (FH*FW)            // 441
#define NIMG (BS*NW*(NS+NQ))    // 100
#define IMG_ELEMS (FDIM*NPOS)   // 28224
#define NY (NS*NPOS)            // 2205
#define TY 64                   // support tile size (vectors per LDS tile)

// Kernel A: per-(img,pos) L2 normalize over channels, store channel-contiguous
__global__ void dn4_normalize(const float* __restrict__ fm, float* __restrict__ normT) {
    int gid = blockIdx.x * blockDim.x + threadIdx.x;
    if (gid >= NIMG * NPOS) return;
    int img = gid / NPOS;
    int pos = gid - img * NPOS;
    const float* src = fm + (size_t)img * IMG_ELEMS + pos;
    float v[FDIM];
    float ss = 0.f;
#pragma unroll
    for (int c = 0; c < FDIM; ++c) {
        float x = src[(size_t)c * NPOS];
        v[c] = x;
        ss += x * x;
    }
    float rn = 1.0f / (sqrtf(ss) + 1e-12f);
    float* dst = normT + (size_t)img * IMG_ELEMS + (size_t)pos * FDIM;
#pragma unroll
    for (int c = 0; c < FDIM; ++c) dst[c] = v[c] * rn;
}

// Kernel B: one block per (b, q, w). 448 threads, thread t handles x-row t.
__global__ __launch_bounds__(448) void dn4_sim(const float* __restrict__ normT,
                                               const int* __restrict__ elabel,
                                               float* __restrict__ out) {
    __shared__ float sup[TY * FDIM];   // 16 KB
    __shared__ float red[8];

    int bid = blockIdx.x;                 // bid == (b*25+q)*5 + w  (matches pred flat index)
    int w  = bid % NW;
    int q  = (bid / NW) % (NW * NQ);
    int b  = bid / (NW * NW * NQ);
    int wq = q / NQ, qi = q % NQ;
    int img_q = (b * NW + wq) * (NS + NQ) + NS + qi;
    const float* supBase = normT + (size_t)((b * NW + w) * (NS + NQ)) * IMG_ELEMS; // 2205*64 floats contiguous

    int t = threadIdx.x;
    int x = (t < NPOS) ? t : (NPOS - 1);

    // query vector into registers (16 x float4)
    const float4* qp = reinterpret_cast<const float4*>(normT + (size_t)img_q * IMG_ELEMS + (size_t)x * FDIM);
    float4 qv[16];
#pragma unroll
    for (int k = 0; k < 16; ++k) qv[k] = qp[k];

    float t0 = -INFINITY, t1 = -INFINITY, t2 = -INFINITY;

    for (int y0 = 0; y0 < NY; y0 += TY) {
        __syncthreads();
        // cooperative load: TY*16 float4s
        for (int i = t; i < TY * 16; i += 448) {
            int yy = i >> 4, k4 = i & 15;
            int y = y0 + yy;
            float4 val = (y < NY)
                ? reinterpret_cast<const float4*>(supBase + (size_t)y * FDIM)[k4]
                : make_float4(0.f, 0.f, 0.f, 0.f);
            reinterpret_cast<float4*>(sup)[i] = val;
        }
        __syncthreads();

        int ylim = min(TY, NY - y0);
        for (int yy = 0; yy < ylim; ++yy) {
            const float4* sv = reinterpret_cast<const float4*>(sup + yy * FDIM);
            float4 acc = make_float4(0.f, 0.f, 0.f, 0.f);
#pragma unroll
            for (int k = 0; k < 16; ++k) {
                float4 s = sv[k];
                acc.x += qv[k].x * s.x;
                acc.y += qv[k].y * s.y;
                acc.z += qv[k].z * s.z;
                acc.w += qv[k].w * s.w;
            }
            float d = (acc.x + acc.y) + (acc.z + acc.w);
            // branchless top-3 update
            float m  = fminf(d, t0);  t0 = fmaxf(d, t0);
            float m2 = fminf(m, t1);  t1 = fmaxf(m, t1);
            t2 = fmaxf(m2, t2);
        }
    }

    float s = (t < NPOS) ? (t0 + t1 + t2) : 0.f;
    // butterfly wave reduce (64 lanes)
#pragma unroll
    for (int off = 32; off >= 1; off >>= 1) s += __shfl_xor(s, off, 64);
    int wave = t >> 6, lane = t & 63;
    if (lane == 0) red[wave] = s;
    __syncthreads();
    if (t == 0) {
        float tot = 0.f;
#pragma unroll
        for (int i = 0; i < 7; ++i) tot += red[i];
        out[bid] = tot;
        if (bid < BS * NW * NQ) {   // 50 label pass-throughs
            int bb = bid / (NW * NQ), rem = bid % (NW * NQ);
            int wqe = rem / NQ, qie = rem % NQ;
            out[BS * NW * NQ * NW + bid] = (float)elabel[(bb * NW + wqe) * (NS + NQ) + NS + qie];
        }
    }
}

extern "C" void kernel_launch(void* const* d_in, const int* in_sizes, int n_in,
                              void* d_out, int out_size, void* d_ws, size_t ws_size,
                              hipStream_t stream) {
    const float* fm     = (const float*)d_in[0];
    const int*   elabel = (const int*)d_in[1];
    float* out = (float*)d_out;
    float* normT = (float*)d_ws;   // 100*441*64 floats = 11.3 MB

    int nthreads = NIMG * NPOS;
    dn4_normalize<<<(nthreads + 255) / 256, 256, 0, stream>>>(fm, normT);
    dn4_sim<<<BS * NW * NQ * NW, 448, 0, stream>>>(normT, elabel, out);
}

// Round 2
// 106.637 us; speedup vs baseline: 10.3716x; 10.3716x over previous
//
#include <hip/hip_runtime.h>
#include <hip/hip_bf16.h>
#include <math.h>

// Problem constants (fixed by setup_inputs)
#define BS 2
#define NW 5
#define NS 5
#define NQ 5
#define FDIM 64
#define FH 21
#define FW 21
#define NPOS (FH*FW)            // 441
#define NIMG (BS*NW*(NS+NQ))    // 100
#define IMG_ELEMS (FDIM*NPOS)   // 28224
#define NY (NS*NPOS)            // 2205
#define QROWS 448               // 441 padded to 28*16
#define SROWS 2208              // 2205 padded to 138*16
#define NXT 28                  // x-tiles of 16
#define NYT 138                 // y-tiles of 16

typedef __attribute__((ext_vector_type(8))) short short8;
typedef __attribute__((ext_vector_type(8))) unsigned short us8;
typedef __attribute__((ext_vector_type(4))) float f32x4;

static __device__ __forceinline__ unsigned short f2bf(float x) {
    union { float f; unsigned u; } v; v.f = x;
    unsigned r = v.u + 0x7fffu + ((v.u >> 16) & 1u);   // RNE; inputs are finite
    return (unsigned short)(r >> 16);
}

// Kernel A: L2-normalize per (img,pos) over channels; emit bf16 channel-contiguous
// Q layout: [img][QROWS][64]; S layout: [b*5+w][SROWS][64] (support rows y = s*441+pos)
__global__ __launch_bounds__(256) void dn4_normalize(const float* __restrict__ fm,
                                                     const int* __restrict__ elabel,
                                                     unsigned short* __restrict__ Qn,
                                                     unsigned short* __restrict__ Sn,
                                                     float* __restrict__ out) {
    int gid = blockIdx.x * blockDim.x + threadIdx.x;
    if (gid < 50) {   // label pass-through: out[250+gid]
        int bb = gid / 25, rem = gid % 25, wq = rem / 5, qi = rem % 5;
        out[250 + gid] = (float)elabel[(bb * NW + wq) * (NS + NQ) + NS + qi];
    }
    if (gid >= NIMG * NPOS) return;
    int img = gid / NPOS;
    int pos = gid - img * NPOS;
    const float* src = fm + (size_t)img * IMG_ELEMS + pos;
    float v[FDIM];
    float ss = 0.f;
#pragma unroll
    for (int c = 0; c < FDIM; ++c) {
        float x = src[(size_t)c * NPOS];
        v[c] = x;
        ss += x * x;
    }
    float rn = 1.0f / (sqrtf(ss) + 1e-12f);
    unsigned short tmp[FDIM];
#pragma unroll
    for (int c = 0; c < FDIM; ++c) tmp[c] = f2bf(v[c] * rn);

    us8* qd = (us8*)(Qn + (size_t)img * (QROWS * FDIM) + (size_t)pos * FDIM);
#pragma unroll
    for (int k = 0; k < 8; ++k) qd[k] = *(const us8*)(tmp + 8 * k);

    int i10 = img % 10;
    if (i10 < NS) {  // support image -> also write S
        int bw = img / 10;            // b*5+w
        int y = i10 * NPOS + pos;
        us8* sd = (us8*)(Sn + (size_t)bw * (SROWS * FDIM) + (size_t)y * FDIM);
#pragma unroll
        for (int k = 0; k < 8; ++k) sd[k] = *(const us8*)(tmp + 8 * k);
    }
}

#define TOP3_INS(d, a0, a1, a2) do { \
    float _m  = fminf((d), (a0)); (a0) = fmaxf((d), (a0)); \
    float _m2 = fminf(_m, (a1));  (a1) = fmaxf(_m, (a1));  \
    (a2) = fmaxf(_m2, (a2)); } while (0)

// Kernel B: one block per (b,q,w); 4 waves; wave wv owns x-tiles {wv, wv+4, ...} (7 each).
// MFMA 16x16x32 bf16, fragments loaded straight from global (L2/L3 resident).
__global__ __launch_bounds__(256) void dn4_sim_mfma(const unsigned short* __restrict__ Qn,
                                                    const unsigned short* __restrict__ Sn,
                                                    float* __restrict__ out) {
    __shared__ float red[4];
    int bid = blockIdx.x;                 // (b*25+q)*5 + w
    int w = bid % NW;
    int q = (bid / NW) % (NW * NQ);
    int b = bid / (NW * NW * NQ);
    int wq = q / NQ, qi = q % NQ;
    int img_q = (b * NW + wq) * (NS + NQ) + NS + qi;

    const unsigned short* qbase = Qn + (size_t)img_q * (QROWS * FDIM);
    const unsigned short* sbase = Sn + (size_t)(b * NW + w) * (SROWS * FDIM);

    int t = threadIdx.x;
    int lane = t & 63, wv = t >> 6;
    int lo16 = lane & 15, hi4 = lane >> 4;

    // A fragments: row = lo16, k = h*32 + hi4*8 .. +8
    short8 afr[7][2];
#pragma unroll
    for (int i = 0; i < 7; ++i) {
        int xt = wv + 4 * i;
        const unsigned short* qp = qbase + (size_t)(xt * 16 + lo16) * FDIM + hi4 * 8;
        afr[i][0] = *(const short8*)(qp);
        afr[i][1] = *(const short8*)(qp + 32);
    }

    float t0[7][4], t1[7][4], t2[7][4];
#pragma unroll
    for (int i = 0; i < 7; ++i)
#pragma unroll
        for (int r = 0; r < 4; ++r) { t0[i][r] = -3e38f; t1[i][r] = -3e38f; t2[i][r] = -3e38f; }

    // B fragments: col = lo16, k = h*32 + hi4*8 .. +8  (same addressing shape as A)
    const unsigned short* sp0 = sbase + (size_t)lo16 * FDIM + hi4 * 8;
    short8 cb0 = *(const short8*)(sp0);
    short8 cb1 = *(const short8*)(sp0 + 32);

    for (int yt = 0; yt < NYT; ++yt) {
        short8 nb0 = cb0, nb1 = cb1;
        if (yt < NYT - 1) {
            const unsigned short* np = sp0 + (size_t)(yt + 1) * (16 * FDIM);
            nb0 = *(const short8*)(np);
            nb1 = *(const short8*)(np + 32);
        }
        bool lastm = (yt == NYT - 1) && (lo16 >= 13);   // y >= 2205 -> mask
#pragma unroll
        for (int i = 0; i < 7; ++i) {
            f32x4 acc = {0.f, 0.f, 0.f, 0.f};
            acc = __builtin_amdgcn_mfma_f32_16x16x32_bf16(afr[i][0], cb0, acc, 0, 0, 0);
            acc = __builtin_amdgcn_mfma_f32_16x16x32_bf16(afr[i][1], cb1, acc, 0, 0, 0);
#pragma unroll
            for (int r = 0; r < 4; ++r) {
                float d = lastm ? -3e38f : acc[r];
                TOP3_INS(d, t0[i][r], t1[i][r], t2[i][r]);
            }
        }
        cb0 = nb0; cb1 = nb1;
    }

    // Cross-lane top-3 merge within each 16-lane column group, then row-sum.
    float lsum = 0.f;
#pragma unroll
    for (int i = 0; i < 7; ++i) {
#pragma unroll
        for (int r = 0; r < 4; ++r) {
            float a0 = t0[i][r], a1 = t1[i][r], a2 = t2[i][r];
#pragma unroll
            for (int mk = 1; mk < 16; mk <<= 1) {
                float c0 = __shfl_xor(a0, mk, 64);
                float c1 = __shfl_xor(a1, mk, 64);
                float c2 = __shfl_xor(a2, mk, 64);
                TOP3_INS(c0, a0, a1, a2);
                TOP3_INS(c1, a0, a1, a2);
                TOP3_INS(c2, a0, a1, a2);
            }
            int x = (wv + 4 * i) * 16 + hi4 * 4 + r;
            float rsum = (x < NPOS && lo16 == 0) ? (a0 + a1 + a2) : 0.f;
            lsum += rsum;
        }
    }
    // 64-lane butterfly sum, then cross-wave via LDS
#pragma unroll
    for (int off = 32; off >= 1; off >>= 1) lsum += __shfl_xor(lsum, off, 64);
    if (lane == 0) red[wv] = lsum;
    __syncthreads();
    if (t == 0) out[bid] = red[0] + red[1] + red[2] + red[3];
}

extern "C" void kernel_launch(void* const* d_in, const int* in_sizes, int n_in,
                              void* d_out, int out_size, void* d_ws, size_t ws_size,
                              hipStream_t stream) {
    const float* fm     = (const float*)d_in[0];
    const int*   elabel = (const int*)d_in[1];
    float* out = (float*)d_out;

    unsigned short* Qn = (unsigned short*)d_ws;                         // 100*448*64 ushort = 5.73 MB
    unsigned short* Sn = Qn + (size_t)NIMG * QROWS * FDIM;              // 10*2208*64 ushort = 2.83 MB

    int nthreads = NIMG * NPOS;
    dn4_normalize<<<(nthreads + 255) / 256, 256, 0, stream>>>(fm, elabel, Qn, Sn, out);
    dn4_sim_mfma<<<BS * NW * NQ * NW, 256, 0, stream>>>(Qn, Sn, out);
}

// Round 3
// 87.868 us; speedup vs baseline: 12.5870x; 1.2136x over previous
//
#include <hip/hip_runtime.h>
#include <hip/hip_bf16.h>
#include <math.h>

// Problem constants (fixed by setup_inputs)
#define BS 2
#define NW 5
#define NS 5
#define NQ 5
#define FDIM 64
#define FH 21
#define FW 21
#define NPOS (FH*FW)            // 441
#define NIMG (BS*NW*(NS+NQ))    // 100
#define IMG_ELEMS (FDIM*NPOS)   // 28224
#define NY (NS*NPOS)            // 2205
#define QROWS 448               // 441 padded to 28*16
#define SROWS 2224              // 2208 used + 16 rows prefetch overrun
#define NYT 138                 // y-tiles of 16 (2208 rows)
#define YHALF 69                // y-tiles per half

typedef __attribute__((ext_vector_type(8))) short short8;
typedef __attribute__((ext_vector_type(8))) unsigned short us8;
typedef __attribute__((ext_vector_type(4))) float f32x4;

static __device__ __forceinline__ unsigned short f2bf(float x) {
    union { float f; unsigned u; } v; v.f = x;
    unsigned r = v.u + 0x7fffu + ((v.u >> 16) & 1u);   // RNE; inputs finite
    return (unsigned short)(r >> 16);
}

// Insert d into sorted top-3 (a0>=a1>=a2): 3 independent VALU ops via med3
#define T3INS(d, a0, a1, a2) do { \
    float _n0 = fmaxf((d), (a0)); \
    float _n1 = __builtin_amdgcn_fmed3f((d), (a0), (a1)); \
    float _n2 = __builtin_amdgcn_fmed3f((d), (a1), (a2)); \
    (a0) = _n0; (a1) = _n1; (a2) = _n2; } while (0)

// Kernel A: L2-normalize per (img,pos); emit bf16 channel-contiguous.
// Query images -> Qn[img][QROWS][64]; support images -> Sn[b*5+w][SROWS][64].
// Also zeroes S pad rows (y=2205..2207) and writes the 50 label pass-throughs.
__global__ __launch_bounds__(256) void dn4_normalize(const float* __restrict__ fm,
                                                     const int* __restrict__ elabel,
                                                     unsigned short* __restrict__ Qn,
                                                     unsigned short* __restrict__ Sn,
                                                     float* __restrict__ out) {
    int gid = blockIdx.x * blockDim.x + threadIdx.x;
    if (gid < 50) {   // label pass-through: out[250+gid]
        int bb = gid / 25, rem = gid % 25, wq = rem / 5, qi = rem % 5;
        out[250 + gid] = (float)elabel[(bb * NW + wq) * (NS + NQ) + NS + qi];
    }
    if (gid < 240) {  // zero S pad rows: 10 mats x 3 rows x 8 us8
        int mat = gid / 24, rr = (gid % 24) >> 3, k8 = gid & 7;
        us8 zv = {0,0,0,0,0,0,0,0};
        *(us8*)(Sn + (size_t)mat * (SROWS * FDIM) + (size_t)(NY + rr) * FDIM + k8 * 8) = zv;
    }
    if (gid >= NIMG * NPOS) return;
    int img = gid / NPOS;
    int pos = gid - img * NPOS;
    const float* src = fm + (size_t)img * IMG_ELEMS + pos;
    float v[FDIM];
    float ss = 0.f;
#pragma unroll
    for (int c = 0; c < FDIM; ++c) {
        float x = src[(size_t)c * NPOS];
        v[c] = x;
        ss += x * x;
    }
    float rn = 1.0f / (sqrtf(ss) + 1e-12f);
    unsigned short tmp[FDIM];
#pragma unroll
    for (int c = 0; c < FDIM; ++c) tmp[c] = f2bf(v[c] * rn);

    int i10 = img % 10;
    if (i10 < NS) {  // support image
        int bw = img / 10;            // b*5+w
        int y = i10 * NPOS + pos;
        us8* sd = (us8*)(Sn + (size_t)bw * (SROWS * FDIM) + (size_t)y * FDIM);
#pragma unroll
        for (int k = 0; k < 8; ++k) sd[k] = *(const us8*)(tmp + 8 * k);
    } else {         // query image
        us8* qd = (us8*)(Qn + (size_t)img * (QROWS * FDIM) + (size_t)pos * FDIM);
#pragma unroll
        for (int k = 0; k < 8; ++k) qd[k] = *(const us8*)(tmp + 8 * k);
    }
}

// Kernel B: one block per (b,q,w); 896 threads = 14 waves:
//   wave wv: xg = wv%7 (owns x-tiles xg*4..xg*4+3), yh = wv/7 (y-tiles [yh*69, yh*69+69)).
// Y-halves merged via LDS top-3 buffer at the end.
__global__ __launch_bounds__(896) void dn4_sim_mfma(const unsigned short* __restrict__ Qn,
                                                    const unsigned short* __restrict__ Sn,
                                                    float* __restrict__ out) {
    __shared__ float top3buf[2][QROWS][3];   // 10.5 KB
    __shared__ float red[14];

    int bid = blockIdx.x;                 // (b*25+q)*5 + w == pred flat index
    int w = bid % NW;
    int q = (bid / NW) % (NW * NQ);
    int b = bid / (NW * NW * NQ);
    int wq = q / NQ, qi = q % NQ;
    int img_q = (b * NW + wq) * (NS + NQ) + NS + qi;

    const unsigned short* qbase = Qn + (size_t)img_q * (QROWS * FDIM);
    const unsigned short* sbase = Sn + (size_t)(b * NW + w) * (SROWS * FDIM);

    int t = threadIdx.x;
    int lane = t & 63, wv = t >> 6;
    int xg = wv % 7, yh = wv / 7;
    int lo16 = lane & 15, hi4 = lane >> 4;

    // A fragments: 4 x-tiles, row = lo16, k = h*32 + hi4*8 .. +8
    short8 afr[4][2];
#pragma unroll
    for (int i = 0; i < 4; ++i) {
        int xt = xg * 4 + i;
        const unsigned short* qp = qbase + (size_t)(xt * 16 + lo16) * FDIM + hi4 * 8;
        afr[i][0] = *(const short8*)(qp);
        afr[i][1] = *(const short8*)(qp + 32);
    }

    float t0[4][4], t1[4][4], t2[4][4];
#pragma unroll
    for (int i = 0; i < 4; ++i)
#pragma unroll
        for (int r = 0; r < 4; ++r) { t0[i][r] = -3e38f; t1[i][r] = -3e38f; t2[i][r] = -3e38f; }

    f32x4 z = {0.f, 0.f, 0.f, 0.f};   // persistent zero C-in (no per-iter v_movs)

    const unsigned short* sp0 = sbase + (size_t)lo16 * FDIM + hi4 * 8;
    int ybeg = yh * YHALF, yend = ybeg + YHALF;
    const unsigned short* sp = sp0 + (size_t)ybeg * (16 * FDIM);
    short8 cb0 = *(const short8*)(sp);
    short8 cb1 = *(const short8*)(sp + 32);

    for (int yt = ybeg; yt < yend; ++yt) {
        const unsigned short* np = sp0 + (size_t)(yt + 1) * (16 * FDIM);  // overrun tile allocated
        short8 nb0 = *(const short8*)(np);
        short8 nb1 = *(const short8*)(np + 32);
#pragma unroll
        for (int i = 0; i < 4; ++i) {
            f32x4 acc = __builtin_amdgcn_mfma_f32_16x16x32_bf16(afr[i][0], cb0, z, 0, 0, 0);
            acc = __builtin_amdgcn_mfma_f32_16x16x32_bf16(afr[i][1], cb1, acc, 0, 0, 0);
#pragma unroll
            for (int r = 0; r < 4; ++r) T3INS(acc[r], t0[i][r], t1[i][r], t2[i][r]);
        }
        cb0 = nb0; cb1 = nb1;
    }

    // Cross-lane top-3 merge within each 16-lane column group
#pragma unroll
    for (int i = 0; i < 4; ++i) {
#pragma unroll
        for (int r = 0; r < 4; ++r) {
            float a0 = t0[i][r], a1 = t1[i][r], a2 = t2[i][r];
#pragma unroll
            for (int mk = 1; mk < 16; mk <<= 1) {
                float c0 = __shfl_xor(a0, mk, 64);
                float c1 = __shfl_xor(a1, mk, 64);
                float c2 = __shfl_xor(a2, mk, 64);
                T3INS(c0, a0, a1, a2);
                T3INS(c1, a0, a1, a2);
                T3INS(c2, a0, a1, a2);
            }
            if (lo16 == 0) {
                int x = (xg * 4 + i) * 16 + hi4 * 4 + r;
                top3buf[yh][x][0] = a0;
                top3buf[yh][x][1] = a1;
                top3buf[yh][x][2] = a2;
            }
        }
    }
    __syncthreads();

    // Merge the two y-halves per x, sum top-3, block-reduce
    float s = 0.f;
    if (t < QROWS) {
        int x = t;
        float a0 = top3buf[0][x][0], a1 = top3buf[0][x][1], a2 = top3buf[0][x][2];
        float b0 = top3buf[1][x][0], b1 = top3buf[1][x][1], b2 = top3buf[1][x][2];
        T3INS(b0, a0, a1, a2);
        T3INS(b1, a0, a1, a2);
        T3INS(b2, a0, a1, a2);
        s = (x < NPOS) ? (a0 + a1 + a2) : 0.f;
    }
#pragma unroll
    for (int off = 32; off >= 1; off >>= 1) s += __shfl_xor(s, off, 64);
    if (lane == 0) red[wv] = s;
    __syncthreads();
    if (t == 0) {
        float tot = 0.f;
#pragma unroll
        for (int i = 0; i < 14; ++i) tot += red[i];
        out[bid] = tot;
    }
}

extern "C" void kernel_launch(void* const* d_in, const int* in_sizes, int n_in,
                              void* d_out, int out_size, void* d_ws, size_t ws_size,
                              hipStream_t stream) {
    const float* fm     = (const float*)d_in[0];
    const int*   elabel = (const int*)d_in[1];
    float* out = (float*)d_out;

    unsigned short* Qn = (unsigned short*)d_ws;                         // 100*448*64 ushort = 5.73 MB
    unsigned short* Sn = Qn + (size_t)NIMG * QROWS * FDIM;              // 10*2224*64 ushort = 2.85 MB

    int nthreads = NIMG * NPOS;
    dn4_normalize<<<(nthreads + 255) / 256, 256, 0, stream>>>(fm, elabel, Qn, Sn, out);
    dn4_sim_mfma<<<BS * NW * NQ * NW, 896, 0, stream>>>(Qn, Sn, out);
}

// Round 4
// 75.510 us; speedup vs baseline: 14.6469x; 1.1637x over previous
//
#include <hip/hip_runtime.h>
#include <hip/hip_bf16.h>
#include <math.h>

// Problem constants (fixed by setup_inputs)
#define BS 2
#define NW 5
#define NS 5
#define NQ 5
#define FDIM 64
#define FH 21
#define FW 21
#define NPOS (FH*FW)            // 441
#define NIMG (BS*NW*(NS+NQ))    // 100
#define IMG_ELEMS (FDIM*NPOS)   // 28224
#define NY (NS*NPOS)            // 2205
#define QROWS 448               // 441 padded to 28*16
#define SROWS 2224              // 2208 used + 16 rows prefetch overrun
#define NYT 138                 // y-tiles of 16 (2208 rows)
#define YHALF 69                // y-tiles per half

typedef __attribute__((ext_vector_type(8))) short short8;
typedef __attribute__((ext_vector_type(8))) unsigned short us8;
typedef __attribute__((ext_vector_type(4))) float f32x4;

static __device__ __forceinline__ unsigned short f2bf(float x) {
    union { float f; unsigned u; } v; v.f = x;
    unsigned r = v.u + 0x7fffu + ((v.u >> 16) & 1u);   // RNE; inputs finite
    return (unsigned short)(r >> 16);
}

// Insert d into sorted top-3 (a0>=a1>=a2): 3 independent VALU ops via med3
#define T3INS(d, a0, a1, a2) do { \
    float _n0 = fmaxf((d), (a0)); \
    float _n1 = __builtin_amdgcn_fmed3f((d), (a0), (a1)); \
    float _n2 = __builtin_amdgcn_fmed3f((d), (a1), (a2)); \
    (a0) = _n0; (a1) = _n1; (a2) = _n2; } while (0)

// Kernel A: L2-normalize per (img,pos); emit bf16 channel-contiguous.
// Query images -> Qn[img][QROWS][64]; support images -> Sn[b*5+w][SROWS][64].
// Also zeroes S pad rows (y=2205..2207) and writes the 50 label pass-throughs.
__global__ __launch_bounds__(256) void dn4_normalize(const float* __restrict__ fm,
                                                     const int* __restrict__ elabel,
                                                     unsigned short* __restrict__ Qn,
                                                     unsigned short* __restrict__ Sn,
                                                     float* __restrict__ out) {
    int gid = blockIdx.x * blockDim.x + threadIdx.x;
    if (gid < 50) {   // label pass-through: out[250+gid]
        int bb = gid / 25, rem = gid % 25, wq = rem / 5, qi = rem % 5;
        out[250 + gid] = (float)elabel[(bb * NW + wq) * (NS + NQ) + NS + qi];
    }
    if (gid < 240) {  // zero S pad rows: 10 mats x 3 rows x 8 us8
        int mat = gid / 24, rr = (gid % 24) >> 3, k8 = gid & 7;
        us8 zv = {0,0,0,0,0,0,0,0};
        *(us8*)(Sn + (size_t)mat * (SROWS * FDIM) + (size_t)(NY + rr) * FDIM + k8 * 8) = zv;
    }
    if (gid >= NIMG * NPOS) return;
    int img = gid / NPOS;
    int pos = gid - img * NPOS;
    const float* src = fm + (size_t)img * IMG_ELEMS + pos;
    float v[FDIM];
    float ss = 0.f;
#pragma unroll
    for (int c = 0; c < FDIM; ++c) {
        float x = src[(size_t)c * NPOS];
        v[c] = x;
        ss += x * x;
    }
    float rn = 1.0f / (sqrtf(ss) + 1e-12f);
    unsigned short tmp[FDIM];
#pragma unroll
    for (int c = 0; c < FDIM; ++c) tmp[c] = f2bf(v[c] * rn);

    int i10 = img % 10;
    if (i10 < NS) {  // support image
        int bw = img / 10;            // b*5+w
        int y = i10 * NPOS + pos;
        us8* sd = (us8*)(Sn + (size_t)bw * (SROWS * FDIM) + (size_t)y * FDIM);
#pragma unroll
        for (int k = 0; k < 8; ++k) sd[k] = *(const us8*)(tmp + 8 * k);
    } else {         // query image
        us8* qd = (us8*)(Qn + (size_t)img * (QROWS * FDIM) + (size_t)pos * FDIM);
#pragma unroll
        for (int k = 0; k < 8; ++k) qd[k] = *(const us8*)(tmp + 8 * k);
    }
}

// Kernel B: one block per (b,q,w); 896 threads = 14 waves:
//   wave wv: xg = wv%7 (x-tiles xg*4..xg*4+3), yh = wv/7 (y-tiles [yh*69, yh*69+69)).
// TRANSPOSED MFMA: A = S rows (y), B = Q (x) -> D[y_local][x_local], each lane holds
// 4 y-values of ONE x per tile => top-3 state is 3 regs per x-tile (12 total).
// Y-halves merged via LDS top-3 buffer at the end.
__global__ __launch_bounds__(896, 4) void dn4_sim_mfma(const unsigned short* __restrict__ Qn,
                                                       const unsigned short* __restrict__ Sn,
                                                       float* __restrict__ out) {
    __shared__ float top3buf[2][QROWS][3];   // 10.5 KB
    __shared__ float red[14];

    int bid = blockIdx.x;                 // (b*25+q)*5 + w == pred flat index
    int w = bid % NW;
    int q = (bid / NW) % (NW * NQ);
    int b = bid / (NW * NW * NQ);
    int wq = q / NQ, qi = q % NQ;
    int img_q = (b * NW + wq) * (NS + NQ) + NS + qi;

    const unsigned short* qbase = Qn + (size_t)img_q * (QROWS * FDIM);
    const unsigned short* sbase = Sn + (size_t)(b * NW + w) * (SROWS * FDIM);

    int t = threadIdx.x;
    int lane = t & 63, wv = t >> 6;
    int xg = wv % 7, yh = wv / 7;
    int lo16 = lane & 15, hi4 = lane >> 4;

    // B fragments (Q): col = lo16 -> x = xt*16+lo16, k = hi4*8 .. +8 (two K=32 halves)
    short8 bq[4][2];
#pragma unroll
    for (int i = 0; i < 4; ++i) {
        int xt = xg * 4 + i;
        const unsigned short* qp = qbase + (size_t)(xt * 16 + lo16) * FDIM + hi4 * 8;
        bq[i][0] = *(const short8*)(qp);
        bq[i][1] = *(const short8*)(qp + 32);
    }

    // top-3 per x-tile (this lane's x = xt*16+lo16, over y ≡ quarter hi4)
    float t0[4], t1[4], t2[4];
#pragma unroll
    for (int i = 0; i < 4; ++i) { t0[i] = -3e38f; t1[i] = -3e38f; t2[i] = -3e38f; }

    f32x4 z = {0.f, 0.f, 0.f, 0.f};

    // A fragments (S): row = lo16 -> y = yt*16+lo16, k = hi4*8 .. +8
    const unsigned short* sp0 = sbase + (size_t)lo16 * FDIM + hi4 * 8;
    int ybeg = yh * YHALF, yend = ybeg + YHALF;
    const unsigned short* sp = sp0 + (size_t)ybeg * (16 * FDIM);
    short8 ca0 = *(const short8*)(sp);
    short8 ca1 = *(const short8*)(sp + 32);

    for (int yt = ybeg; yt < yend; ++yt) {
        const unsigned short* np = sp0 + (size_t)(yt + 1) * (16 * FDIM);  // overrun tile allocated
        short8 na0 = *(const short8*)(np);
        short8 na1 = *(const short8*)(np + 32);
#pragma unroll
        for (int i = 0; i < 4; ++i) {
            f32x4 acc = __builtin_amdgcn_mfma_f32_16x16x32_bf16(ca0, bq[i][0], z, 0, 0, 0);
            acc = __builtin_amdgcn_mfma_f32_16x16x32_bf16(ca1, bq[i][1], acc, 0, 0, 0);
#pragma unroll
            for (int r = 0; r < 4; ++r) T3INS(acc[r], t0[i], t1[i], t2[i]);
        }
        ca0 = na0; ca1 = na1;
    }

    // Merge top-3 across the 4 y-quarter groups (hi4): xor lanes 16 and 32
#pragma unroll
    for (int i = 0; i < 4; ++i) {
        float a0 = t0[i], a1 = t1[i], a2 = t2[i];
#pragma unroll
        for (int mk = 16; mk <= 32; mk <<= 1) {
            float c0 = __shfl_xor(a0, mk, 64);
            float c1 = __shfl_xor(a1, mk, 64);
            float c2 = __shfl_xor(a2, mk, 64);
            T3INS(c0, a0, a1, a2);
            T3INS(c1, a0, a1, a2);
            T3INS(c2, a0, a1, a2);
        }
        if (hi4 == 0) {
            int x = (xg * 4 + i) * 16 + lo16;
            top3buf[yh][x][0] = a0;
            top3buf[yh][x][1] = a1;
            top3buf[yh][x][2] = a2;
        }
    }
    __syncthreads();

    // Merge the two y-halves per x, sum top-3, block-reduce
    float s = 0.f;
    if (t < QROWS) {
        int x = t;
        float a0 = top3buf[0][x][0], a1 = top3buf[0][x][1], a2 = top3buf[0][x][2];
        float b0 = top3buf[1][x][0], b1 = top3buf[1][x][1], b2 = top3buf[1][x][2];
        T3INS(b0, a0, a1, a2);
        T3INS(b1, a0, a1, a2);
        T3INS(b2, a0, a1, a2);
        s = (x < NPOS) ? (a0 + a1 + a2) : 0.f;
    }
#pragma unroll
    for (int off = 32; off >= 1; off >>= 1) s += __shfl_xor(s, off, 64);
    if (lane == 0) red[wv] = s;
    __syncthreads();
    if (t == 0) {
        float tot = 0.f;
#pragma unroll
        for (int i = 0; i < 14; ++i) tot += red[i];
        out[bid] = tot;
    }
}

extern "C" void kernel_launch(void* const* d_in, const int* in_sizes, int n_in,
                              void* d_out, int out_size, void* d_ws, size_t ws_size,
                              hipStream_t stream) {
    const float* fm     = (const float*)d_in[0];
    const int*   elabel = (const int*)d_in[1];
    float* out = (float*)d_out;

    unsigned short* Qn = (unsigned short*)d_ws;                         // 100*448*64 ushort = 5.73 MB
    unsigned short* Sn = Qn + (size_t)NIMG * QROWS * FDIM;              // 10*2224*64 ushort = 2.85 MB

    int nthreads = NIMG * NPOS;
    dn4_normalize<<<(nthreads + 255) / 256, 256, 0, stream>>>(fm, elabel, Qn, Sn, out);
    dn4_sim_mfma<<<BS * NW * NQ * NW, 896, 0, stream>>>(Qn, Sn, out);
}

// Round 5
// 73.025 us; speedup vs baseline: 15.1454x; 1.0340x over previous
//
#include <hip/hip_runtime.h>
#include <hip/hip_bf16.h>
#include <math.h>

// Problem constants (fixed by setup_inputs)
#define BS 2
#define NW 5
#define NS 5
#define NQ 5
#define FDIM 64
#define FH 21
#define FW 21
#define NPOS (FH*FW)            // 441
#define NIMG (BS*NW*(NS+NQ))    // 100
#define IMG_ELEMS (FDIM*NPOS)   // 28224
#define NY (NS*NPOS)            // 2205
#define QROWS 448               // 441 padded to 28*16
#define SROWS 2256              // 2208 used + 48 rows (3-tile) prefetch overrun
#define NYT 138                 // y-tiles of 16 (2208 rows)
#define YHALF 69                // y-tiles per half (= 3*23, matches unroll-3)
#define NBLK 250

typedef __attribute__((ext_vector_type(8))) short short8;
typedef __attribute__((ext_vector_type(8))) unsigned short us8;
typedef __attribute__((ext_vector_type(4))) float f32x4;

static __device__ __forceinline__ unsigned short f2bf(float x) {
    union { float f; unsigned u; } v; v.f = x;
    unsigned r = v.u + 0x7fffu + ((v.u >> 16) & 1u);   // RNE; inputs finite
    return (unsigned short)(r >> 16);
}

// Insert d into sorted top-3 (a0>=a1>=a2): 3 independent VALU ops via med3
#define T3INS(d, a0, a1, a2) do { \
    float _n0 = fmaxf((d), (a0)); \
    float _n1 = __builtin_amdgcn_fmed3f((d), (a0), (a1)); \
    float _n2 = __builtin_amdgcn_fmed3f((d), (a1), (a2)); \
    (a0) = _n0; (a1) = _n1; (a2) = _n2; } while (0)

// Kernel A: L2-normalize per (img,pos); emit bf16 channel-contiguous.
// Query images -> Qn[img][QROWS][64]; support images -> Sn[b*5+w][SROWS][64].
// Also zeroes S pad rows (y=2205..2207) and writes the 50 label pass-throughs.
__global__ __launch_bounds__(256) void dn4_normalize(const float* __restrict__ fm,
                                                     const int* __restrict__ elabel,
                                                     unsigned short* __restrict__ Qn,
                                                     unsigned short* __restrict__ Sn,
                                                     float* __restrict__ out) {
    int gid = blockIdx.x * blockDim.x + threadIdx.x;
    if (gid < 50) {   // label pass-through: out[250+gid]
        int bb = gid / 25, rem = gid % 25, wq = rem / 5, qi = rem % 5;
        out[250 + gid] = (float)elabel[(bb * NW + wq) * (NS + NQ) + NS + qi];
    }
    if (gid < 240) {  // zero S pad rows: 10 mats x 3 rows x 8 us8
        int mat = gid / 24, rr = (gid % 24) >> 3, k8 = gid & 7;
        us8 zv = {0,0,0,0,0,0,0,0};
        *(us8*)(Sn + (size_t)mat * (SROWS * FDIM) + (size_t)(NY + rr) * FDIM + k8 * 8) = zv;
    }
    if (gid >= NIMG * NPOS) return;
    int img = gid / NPOS;
    int pos = gid - img * NPOS;
    const float* src = fm + (size_t)img * IMG_ELEMS + pos;
    float v[FDIM];
    float ss = 0.f;
#pragma unroll
    for (int c = 0; c < FDIM; ++c) {
        float x = src[(size_t)c * NPOS];
        v[c] = x;
        ss += x * x;
    }
    float rn = 1.0f / (sqrtf(ss) + 1e-12f);
    unsigned short tmp[FDIM];
#pragma unroll
    for (int c = 0; c < FDIM; ++c) tmp[c] = f2bf(v[c] * rn);

    int i10 = img % 10;
    if (i10 < NS) {  // support image
        int bw = img / 10;            // b*5+w
        int y = i10 * NPOS + pos;
        us8* sd = (us8*)(Sn + (size_t)bw * (SROWS * FDIM) + (size_t)y * FDIM);
#pragma unroll
        for (int k = 0; k < 8; ++k) sd[k] = *(const us8*)(tmp + 8 * k);
    } else {         // query image
        us8* qd = (us8*)(Qn + (size_t)img * (QROWS * FDIM) + (size_t)pos * FDIM);
#pragma unroll
        for (int k = 0; k < 8; ++k) qd[k] = *(const us8*)(tmp + 8 * k);
    }
}

// Kernel B: one block per (b,q,w); 896 threads = 14 waves:
//   wave wv: xg = wv%7 (x-tiles xg*4..xg*4+3), yh = wv/7 (y-tiles [yh*69, yh*69+69)).
// TRANSPOSED MFMA (A = S rows, B = Q cols): lane holds 4 y of ONE x -> 3-reg top-3/x-tile.
// 3-deep static prefetch pipeline (6 loads in flight); bijective chunked XCD swizzle.
__global__ __launch_bounds__(896, 4) void dn4_sim_mfma(const unsigned short* __restrict__ Qn,
                                                       const unsigned short* __restrict__ Sn,
                                                       float* __restrict__ out) {
    __shared__ float top3buf[2][QROWS][3];   // 10.5 KB
    __shared__ float red[14];

    // m204 bijective chunked swizzle: consecutive logical bids -> same XCD
    // (same b, overlapping q, all w -> per-XCD L2 working set ~1.9 MB < 4 MB)
    int orig = blockIdx.x;
    int xcd = orig & 7, idx = orig >> 3;
    const int qq = NBLK / 8, rr = NBLK % 8;   // 31, 2
    int bid = (xcd < rr ? xcd * (qq + 1) : rr * (qq + 1) + (xcd - rr) * qq) + idx;

    int w = bid % NW;
    int q = (bid / NW) % (NW * NQ);
    int b = bid / (NW * NW * NQ);
    int wq = q / NQ, qi = q % NQ;
    int img_q = (b * NW + wq) * (NS + NQ) + NS + qi;

    const unsigned short* qbase = Qn + (size_t)img_q * (QROWS * FDIM);
    const unsigned short* sbase = Sn + (size_t)(b * NW + w) * (SROWS * FDIM);

    int t = threadIdx.x;
    int lane = t & 63, wv = t >> 6;
    int xg = wv % 7, yh = wv / 7;
    int lo16 = lane & 15, hi4 = lane >> 4;

    // B fragments (Q): col = lo16 -> x = xt*16+lo16, k = hi4*8 .. +8 (two K=32 halves)
    short8 bq[4][2];
#pragma unroll
    for (int i = 0; i < 4; ++i) {
        int xt = xg * 4 + i;
        const unsigned short* qp = qbase + (size_t)(xt * 16 + lo16) * FDIM + hi4 * 8;
        bq[i][0] = *(const short8*)(qp);
        bq[i][1] = *(const short8*)(qp + 32);
    }

    float t0[4], t1[4], t2[4];
#pragma unroll
    for (int i = 0; i < 4; ++i) { t0[i] = -3e38f; t1[i] = -3e38f; t2[i] = -3e38f; }

    f32x4 z = {0.f, 0.f, 0.f, 0.f};

    // A fragments (S): row = lo16 -> y = yt*16+lo16, k = hi4*8 .. +8
    const unsigned short* sp0 = sbase + (size_t)lo16 * FDIM + hi4 * 8;
    int ybeg = yh * YHALF;

    short8 a0_0, a1_0, a0_1, a1_1, a0_2, a1_2;   // 3 static tile buffers
#define LOADT(j, tile) do { \
        const unsigned short* _p = sp0 + (size_t)(tile) * (16 * FDIM); \
        a0_##j = *(const short8*)(_p); \
        a1_##j = *(const short8*)(_p + 32); } while (0)

#define COMPUTE(j) do { \
        _Pragma("unroll") \
        for (int i = 0; i < 4; ++i) { \
            f32x4 acc = __builtin_amdgcn_mfma_f32_16x16x32_bf16(a0_##j, bq[i][0], z, 0, 0, 0); \
            acc = __builtin_amdgcn_mfma_f32_16x16x32_bf16(a1_##j, bq[i][1], acc, 0, 0, 0); \
            _Pragma("unroll") \
            for (int r = 0; r < 4; ++r) T3INS(acc[r], t0[i], t1[i], t2[i]); \
        } } while (0)

    LOADT(0, ybeg); LOADT(1, ybeg + 1); LOADT(2, ybeg + 2);

    for (int yt = ybeg; yt < ybeg + YHALF; yt += 3) {   // 23 iterations exactly
        COMPUTE(0); LOADT(0, yt + 3);
        COMPUTE(1); LOADT(1, yt + 4);
        COMPUTE(2); LOADT(2, yt + 5);   // overrun tiles allocated (SROWS=2256), never computed
    }

    // Merge top-3 across the 4 y-quarter groups (hi4): xor lanes 16 and 32
#pragma unroll
    for (int i = 0; i < 4; ++i) {
        float a0 = t0[i], a1 = t1[i], a2 = t2[i];
#pragma unroll
        for (int mk = 16; mk <= 32; mk <<= 1) {
            float c0 = __shfl_xor(a0, mk, 64);
            float c1 = __shfl_xor(a1, mk, 64);
            float c2 = __shfl_xor(a2, mk, 64);
            T3INS(c0, a0, a1, a2);
            T3INS(c1, a0, a1, a2);
            T3INS(c2, a0, a1, a2);
        }
        if (hi4 == 0) {
            int x = (xg * 4 + i) * 16 + lo16;
            top3buf[yh][x][0] = a0;
            top3buf[yh][x][1] = a1;
            top3buf[yh][x][2] = a2;
        }
    }
    __syncthreads();

    // Merge the two y-halves per x, sum top-3, block-reduce
    float s = 0.f;
    if (t < QROWS) {
        int x = t;
        float a0 = top3buf[0][x][0], a1 = top3buf[0][x][1], a2 = top3buf[0][x][2];
        float b0 = top3buf[1][x][0], b1 = top3buf[1][x][1], b2 = top3buf[1][x][2];
        T3INS(b0, a0, a1, a2);
        T3INS(b1, a0, a1, a2);
        T3INS(b2, a0, a1, a2);
        s = (x < NPOS) ? (a0 + a1 + a2) : 0.f;
    }
#pragma unroll
    for (int off = 32; off >= 1; off >>= 1) s += __shfl_xor(s, off, 64);
    if (lane == 0) red[wv] = s;
    __syncthreads();
    if (t == 0) {
        float tot = 0.f;
#pragma unroll
        for (int i = 0; i < 14; ++i) tot += red[i];
        out[bid] = tot;
    }
}

extern "C" void kernel_launch(void* const* d_in, const int* in_sizes, int n_in,
                              void* d_out, int out_size, void* d_ws, size_t ws_size,
                              hipStream_t stream) {
    const float* fm     = (const float*)d_in[0];
    const int*   elabel = (const int*)d_in[1];
    float* out = (float*)d_out;

    unsigned short* Qn = (unsigned short*)d_ws;                         // 100*448*64 ushort = 5.73 MB
    unsigned short* Sn = Qn + (size_t)NIMG * QROWS * FDIM;              // 10*2256*64 ushort = 2.89 MB

    int nthreads = NIMG * NPOS;
    dn4_normalize<<<(nthreads + 255) / 256, 256, 0, stream>>>(fm, elabel, Qn, Sn, out);
    dn4_sim_mfma<<<NBLK, 896, 0, stream>>>(Qn, Sn, out);
}

// Round 6
// 64.499 us; speedup vs baseline: 17.1474x; 1.1322x over previous
//
#include <hip/hip_runtime.h>
#include <hip/hip_bf16.h>
#include <math.h>

// Problem constants (fixed by setup_inputs)
#define BS 2
#define NW 5
#define NS 5
#define NQ 5
#define FDIM 64
#define FH 21
#define FW 21
#define NPOS (FH*FW)            // 441
#define NIMG (BS*NW*(NS+NQ))    // 100
#define IMG_ELEMS (FDIM*NPOS)   // 28224
#define NY (NS*NPOS)            // 2205
#define QROWS 448               // 441 padded to 28*16
#define SROWS 2256              // 141 tiles: 138 used + 3 prefetch overrun
#define NYT 138                 // y-tiles of 16 (2208 rows)
#define YHALF 69                // y-tiles per half
#define NBLK 250
#define TILE_USH (16*FDIM)      // 1024 ushorts = 2 KB per tile

typedef __attribute__((ext_vector_type(8))) short short8;
typedef __attribute__((ext_vector_type(8))) unsigned short us8;
typedef __attribute__((ext_vector_type(4))) float f32x4;

static __device__ __forceinline__ unsigned short f2bf(float x) {
    union { float f; unsigned u; } v; v.f = x;
    unsigned r = v.u + 0x7fffu + ((v.u >> 16) & 1u);   // RNE; inputs finite
    return (unsigned short)(r >> 16);
}

static __device__ __forceinline__ void gload_lds16(const unsigned short* g, unsigned short* l) {
    __builtin_amdgcn_global_load_lds((const __attribute__((address_space(1))) void*)g,
                                     (__attribute__((address_space(3))) void*)l, 16, 0, 0);
}

// Insert d into sorted top-3 (a0>=a1>=a2): 3 independent VALU ops via med3
#define T3INS(d, a0, a1, a2) do { \
    float _n0 = fmaxf((d), (a0)); \
    float _n1 = __builtin_amdgcn_fmed3f((d), (a0), (a1)); \
    float _n2 = __builtin_amdgcn_fmed3f((d), (a1), (a2)); \
    (a0) = _n0; (a1) = _n1; (a2) = _n2; } while (0)

// Kernel A: L2-normalize per (img,pos); emit bf16 channel-contiguous.
__global__ __launch_bounds__(256) void dn4_normalize(const float* __restrict__ fm,
                                                     const int* __restrict__ elabel,
                                                     unsigned short* __restrict__ Qn,
                                                     unsigned short* __restrict__ Sn,
                                                     float* __restrict__ out) {
    int gid = blockIdx.x * blockDim.x + threadIdx.x;
    if (gid < 50) {   // label pass-through: out[250+gid]
        int bb = gid / 25, rem = gid % 25, wq = rem / 5, qi = rem % 5;
        out[250 + gid] = (float)elabel[(bb * NW + wq) * (NS + NQ) + NS + qi];
    }
    if (gid < 240) {  // zero S pad rows: 10 mats x 3 rows x 8 us8
        int mat = gid / 24, rr = (gid % 24) >> 3, k8 = gid & 7;
        us8 zv = {0,0,0,0,0,0,0,0};
        *(us8*)(Sn + (size_t)mat * (SROWS * FDIM) + (size_t)(NY + rr) * FDIM + k8 * 8) = zv;
    }
    if (gid >= NIMG * NPOS) return;
    int img = gid / NPOS;
    int pos = gid - img * NPOS;
    const float* src = fm + (size_t)img * IMG_ELEMS + pos;
    float v[FDIM];
    float ss = 0.f;
#pragma unroll
    for (int c = 0; c < FDIM; ++c) {
        float x = src[(size_t)c * NPOS];
        v[c] = x;
        ss += x * x;
    }
    float rn = 1.0f / (sqrtf(ss) + 1e-12f);
    unsigned short tmp[FDIM];
#pragma unroll
    for (int c = 0; c < FDIM; ++c) tmp[c] = f2bf(v[c] * rn);

    int i10 = img % 10;
    if (i10 < NS) {
        int bw = img / 10;
        int y = i10 * NPOS + pos;
        us8* sd = (us8*)(Sn + (size_t)bw * (SROWS * FDIM) + (size_t)y * FDIM);
#pragma unroll
        for (int k = 0; k < 8; ++k) sd[k] = *(const us8*)(tmp + 8 * k);
    } else {
        us8* qd = (us8*)(Qn + (size_t)img * (QROWS * FDIM) + (size_t)pos * FDIM);
#pragma unroll
        for (int k = 0; k < 8; ++k) qd[k] = *(const us8*)(tmp + 8 * k);
    }
}

// Kernel B: one block per (b,q,w); 896 threads = 14 waves: xg = wv%7, yh = wv/7.
// S tiles staged ONCE per y-half into an LDS 3-buffer ring via global_load_lds
// (pre-swizzled global source, linear LDS dest; XOR-swizzled ds_read), depth-2
// pipeline with counted vmcnt(2) and raw per-tile s_barrier. All 7 xg-waves of a
// y-half share the staged tile. TRANSPOSED MFMA (A=S rows, B=Q cols).
__global__ __launch_bounds__(896, 4) void dn4_sim_mfma(const unsigned short* __restrict__ Qn,
                                                       const unsigned short* __restrict__ Sn,
                                                       float* __restrict__ out) {
    __shared__ __align__(16) unsigned short sring[2][3][TILE_USH];   // 12 KB
    __shared__ float top3buf[2][QROWS][3];                           // 10.5 KB
    __shared__ float red[14];

    // m204 bijective chunked XCD swizzle
    int orig = blockIdx.x;
    int xcd = orig & 7, idx = orig >> 3;
    const int qq = NBLK / 8, rr = NBLK % 8;   // 31, 2
    int bid = (xcd < rr ? xcd * (qq + 1) : rr * (qq + 1) + (xcd - rr) * qq) + idx;

    int w = bid % NW;
    int q = (bid / NW) % (NW * NQ);
    int b = bid / (NW * NW * NQ);
    int wq = q / NQ, qi = q % NQ;
    int img_q = (b * NW + wq) * (NS + NQ) + NS + qi;

    const unsigned short* qbase = Qn + (size_t)img_q * (QROWS * FDIM);
    const unsigned short* sbase = Sn + (size_t)(b * NW + w) * (SROWS * FDIM);

    int t = threadIdx.x;
    int lane = t & 63, wv = t >> 6;
    int xg = wv % 7, yh = wv / 7;
    int lo16 = lane & 15, hi4 = lane >> 4;
    bool stageW = (xg == 0);   // wave-uniform: one stage wave per y-half

    // B fragments (Q): col = lo16 -> x = xt*16+lo16, k = hi4*8 .. +8
    short8 bq[4][2];
#pragma unroll
    for (int i = 0; i < 4; ++i) {
        int xt = xg * 4 + i;
        const unsigned short* qp = qbase + (size_t)(xt * 16 + lo16) * FDIM + hi4 * 8;
        bq[i][0] = *(const short8*)(qp);
        bq[i][1] = *(const short8*)(qp + 32);
    }

    float t0[4], t1[4], t2[4];
#pragma unroll
    for (int i = 0; i < 4; ++i) { t0[i] = -3e38f; t1[i] = -3e38f; t2[i] = -3e38f; }

    f32x4 z = {0.f, 0.f, 0.f, 0.f};

    int ybeg = yh * YHALF;

    // Stage source pre-swizzle: LDS linear [row][c] receives global [row][c ^ (row&7)]
    // (c = 16B unit within 128B row). Lane l of stage instr h covers row h*8+(l>>3).
    int stg0 = ((lane >> 3) * FDIM) + (((lane & 7) ^ ((lane >> 3) & 7)) * 8);

    // Swizzled read offsets (ushort units): want col c -> read c ^ (lo16&7)
    int rd_a0 = lo16 * FDIM + ((hi4 ^ (lo16 & 7)) * 8);
    int rd_a1 = lo16 * FDIM + (((4 + hi4) ^ (lo16 & 7)) * 8);

    // Prologue: stage tiles ybeg, ybeg+1 into bufs 0,1
    if (stageW) {
        const unsigned short* g0 = sbase + (size_t)ybeg * TILE_USH + stg0;
        gload_lds16(g0, &sring[yh][0][0]);
        gload_lds16(g0 + 8 * FDIM, &sring[yh][0][0] + 8 * FDIM);
        const unsigned short* g1 = sbase + (size_t)(ybeg + 1) * TILE_USH + stg0;
        gload_lds16(g1, &sring[yh][1][0]);
        gload_lds16(g1 + 8 * FDIM, &sring[yh][1][0] + 8 * FDIM);
        asm volatile("s_waitcnt vmcnt(2)" ::: "memory");   // buf0 (and bq) landed
    }
    asm volatile("s_barrier" ::: "memory");

    int cur = 0, nxt2 = 2;
    for (int tt = 0; tt < YHALF; ++tt) {
        if (stageW) {   // stage tile tt+2 (overrun tiles allocated: SROWS=2256)
            const unsigned short* g = sbase + (size_t)(ybeg + tt + 2) * TILE_USH + stg0;
            unsigned short* d = &sring[yh][nxt2][0];
            gload_lds16(g, d);
            gload_lds16(g + 8 * FDIM, d + 8 * FDIM);
        }
        const unsigned short* bufp = &sring[yh][cur][0];
        short8 ca0 = *(const short8*)(bufp + rd_a0);
        short8 ca1 = *(const short8*)(bufp + rd_a1);
#pragma unroll
        for (int i = 0; i < 4; ++i) {
            f32x4 acc = __builtin_amdgcn_mfma_f32_16x16x32_bf16(ca0, bq[i][0], z, 0, 0, 0);
            acc = __builtin_amdgcn_mfma_f32_16x16x32_bf16(ca1, bq[i][1], acc, 0, 0, 0);
#pragma unroll
            for (int r = 0; r < 4; ++r) T3INS(acc[r], t0[i], t1[i], t2[i]);
        }
        if (stageW) asm volatile("s_waitcnt vmcnt(2)" ::: "memory");  // tile tt+1 ready
        asm volatile("s_barrier" ::: "memory");
        cur = (cur == 2) ? 0 : cur + 1;
        nxt2 = (nxt2 == 2) ? 0 : nxt2 + 1;
    }

    // Merge top-3 across the 4 y-quarter groups (hi4): xor lanes 16 and 32
#pragma unroll
    for (int i = 0; i < 4; ++i) {
        float a0 = t0[i], a1 = t1[i], a2 = t2[i];
#pragma unroll
        for (int mk = 16; mk <= 32; mk <<= 1) {
            float c0 = __shfl_xor(a0, mk, 64);
            float c1 = __shfl_xor(a1, mk, 64);
            float c2 = __shfl_xor(a2, mk, 64);
            T3INS(c0, a0, a1, a2);
            T3INS(c1, a0, a1, a2);
            T3INS(c2, a0, a1, a2);
        }
        if (hi4 == 0) {
            int x = (xg * 4 + i) * 16 + lo16;
            top3buf[yh][x][0] = a0;
            top3buf[yh][x][1] = a1;
            top3buf[yh][x][2] = a2;
        }
    }
    __syncthreads();

    // Merge the two y-halves per x, sum top-3, block-reduce
    float s = 0.f;
    if (t < QROWS) {
        int x = t;
        float a0 = top3buf[0][x][0], a1 = top3buf[0][x][1], a2 = top3buf[0][x][2];
        float b0 = top3buf[1][x][0], b1 = top3buf[1][x][1], b2 = top3buf[1][x][2];
        T3INS(b0, a0, a1, a2);
        T3INS(b1, a0, a1, a2);
        T3INS(b2, a0, a1, a2);
        s = (x < NPOS) ? (a0 + a1 + a2) : 0.f;
    }
#pragma unroll
    for (int off = 32; off >= 1; off >>= 1) s += __shfl_xor(s, off, 64);
    if (lane == 0) red[wv] = s;
    __syncthreads();
    if (t == 0) {
        float tot = 0.f;
#pragma unroll
        for (int i = 0; i < 14; ++i) tot += red[i];
        out[bid] = tot;
    }
}

extern "C" void kernel_launch(void* const* d_in, const int* in_sizes, int n_in,
                              void* d_out, int out_size, void* d_ws, size_t ws_size,
                              hipStream_t stream) {
    const float* fm     = (const float*)d_in[0];
    const int*   elabel = (const int*)d_in[1];
    float* out = (float*)d_out;

    unsigned short* Qn = (unsigned short*)d_ws;                         // 100*448*64 ushort
    unsigned short* Sn = Qn + (size_t)NIMG * QROWS * FDIM;              // 10*2256*64 ushort

    int nthreads = NIMG * NPOS;
    dn4_normalize<<<(nthreads + 255) / 256, 256, 0, stream>>>(fm, elabel, Qn, Sn, out);
    dn4_sim_mfma<<<NBLK, 896, 0, stream>>>(Qn, Sn, out);
}